// Round 5
// baseline (753.430 us; speedup 1.0000x reference)
//
#include <hip/hip_runtime.h>
#include <float.h>

// Problem constants
#define N_PTS    32768       // 8*16*16*16 spatial positions
#define N_CODES  2048
#define DIM      256
#define S_STRIDE 4096        // d*h*w stride of channel dim in z (floats)
#define B_STRIDE 1048576     // per-batch stride in z (256*4096 floats)
#define N_ELEM   8388608     // total z elements

#define MARGIN   4e-4f       // screening slack; np-vs-screen score error bound ~2.1e-4
#define CAP      4           // candidate slots per point

// ws layout (bytes), 16-aligned
#define WS_LOSS   0          // float
#define WS_OVCNT  8          // int
#define WS_E2     16         // float[2048]                -> 8208
#define WS_Z2     8208       // float[32768]               -> 139280
#define WS_IDX    139280     // int[32768]                 -> 270352
#define WS_EB     270352     // ushort bf16[2048*256]      -> 1318928
#define WS_CNT    1318928    // int[32768]                 -> 1450000
#define WS_CAND   1450000    // int[32768*4]               -> 1974288
#define WS_OV     1974288    // int[8192]                  -> 2007056

typedef unsigned short ushort_t;
typedef short bf16x8 __attribute__((ext_vector_type(8)));
typedef float f32x4 __attribute__((ext_vector_type(4)));

__device__ __forceinline__ ushort_t f2bf(float v) {   // RNE fp32->bf16 (no NaN in data)
    const unsigned u = __float_as_uint(v);
    return (ushort_t)((u + 0x7FFFu + ((u >> 16) & 1u)) >> 16);
}

__global__ void init_kernel(float* loss, int* ovcount, int* cnt) {
    const int i = blockIdx.x * 256 + threadIdx.x;
    if (i < N_PTS) cnt[i] = 0;
    if (i == 0) { *loss = 0.f; *ovcount = 0; }
}

// emb fp32 -> bf16 copy (for MFMA screening)
__global__ void conv_emb_kernel(const float* __restrict__ emb, ushort_t* __restrict__ eb) {
    const int i = blockIdx.x * 256 + threadIdx.x;    // 512 blocks x 4 elems
    const float4 u = *reinterpret_cast<const float4*>(emb + (size_t)i * 4);
    ushort4 v; v.x = f2bf(u.x); v.y = f2bf(u.y); v.z = f2bf(u.z); v.w = f2bf(u.w);
    *reinterpret_cast<ushort4*>(eb + (size_t)i * 4) = v;
}

// numpy pairwise-sum emulation (n=256): two 128-blocks of 8 accumulators.
__global__ void e2_kernel(const float* __restrict__ emb, float* __restrict__ e2) {
    const int k = blockIdx.x * 256 + threadIdx.x;
    const float* base = emb + (size_t)k * DIM;
    float half[2];
    #pragma unroll
    for (int h = 0; h < 2; ++h) {
        float r[8];
        #pragma unroll
        for (int j = 0; j < 8; ++j) { const float v = base[h * 128 + j]; r[j] = __fmul_rn(v, v); }
        for (int t = 8; t < 128; t += 8)
            #pragma unroll
            for (int j = 0; j < 8; ++j) {
                const float v = base[h * 128 + t + j];
                r[j] = __fadd_rn(r[j], __fmul_rn(v, v));
            }
        half[h] = __fadd_rn(__fadd_rn(__fadd_rn(r[0], r[1]), __fadd_rn(r[2], r[3])),
                            __fadd_rn(__fadd_rn(r[4], r[5]), __fadd_rn(r[6], r[7])));
    }
    e2[k] = __fadd_rn(half[0], half[1]);
}

__global__ void z2_kernel(const float* __restrict__ z, float* __restrict__ z2) {
    const int n = blockIdx.x * 256 + threadIdx.x;
    const int b = n >> 12, s = n & 4095;
    const float* base = z + (size_t)b * B_STRIDE + s;
    float half[2];
    #pragma unroll
    for (int h = 0; h < 2; ++h) {
        float r[8];
        #pragma unroll
        for (int j = 0; j < 8; ++j) {
            const float v = base[(size_t)(h * 128 + j) * S_STRIDE];
            r[j] = __fmul_rn(v, v);
        }
        for (int t = 8; t < 128; t += 8)
            #pragma unroll
            for (int j = 0; j < 8; ++j) {
                const float v = base[(size_t)(h * 128 + t + j) * S_STRIDE];
                r[j] = __fadd_rn(r[j], __fmul_rn(v, v));
            }
        half[h] = __fadd_rn(__fadd_rn(__fadd_rn(r[0], r[1]), __fadd_rn(r[2], r[3])),
                            __fadd_rn(__fadd_rn(r[4], r[5]), __fadd_rn(r[6], r[7])));
    }
    z2[n] = __fadd_rn(half[0], half[1]);
}

// bf16-MFMA screening: pass1 exact min of screen-score per point, pass2 collect
// all codes within MARGIN (bit-identical recompute).  Block: 64 pts x 2048 codes.
// Screen score (z2-shifted, ordering-equivalent): s~ = e2[k] - 2*dot_bf16.
__global__ __launch_bounds__(256) void screen_kernel(
    const float* __restrict__ z, const ushort_t* __restrict__ eb,
    const float* __restrict__ e2, int* __restrict__ cnt, int* __restrict__ cand,
    int* __restrict__ ovlist, int* __restrict__ ovcount)
{
    __shared__ ushort_t zt[64 * 264];   // bf16 A-tile [p][c], +8 pad -> b128 reads bank-balanced
    __shared__ float e2s[N_CODES];      // 8 KB
    __shared__ float rmin[64];
    const int tid = threadIdx.x;
    const int n0 = blockIdx.x * 64;
    const int b = n0 >> 12, s0 = n0 & 4095;
    for (int i = tid; i < N_CODES; i += 256) e2s[i] = e2[i];
    {
        const int tq = tid & 15, cg = tid >> 4;
        for (int c = cg; c < DIM; c += 16) {
            const float4 u = *reinterpret_cast<const float4*>(
                z + (size_t)b * B_STRIDE + (size_t)c * S_STRIDE + s0 + tq * 4);
            zt[(tq * 4 + 0) * 264 + c] = f2bf(u.x);
            zt[(tq * 4 + 1) * 264 + c] = f2bf(u.y);
            zt[(tq * 4 + 2) * 264 + c] = f2bf(u.z);
            zt[(tq * 4 + 3) * 264 + c] = f2bf(u.w);
        }
    }
    __syncthreads();
    const int wv = tid >> 6, lane = tid & 63;
    const int col = lane & 15, quad = lane >> 4;
    const ushort_t* ap = &zt[(wv * 16 + col) * 264 + quad * 8];   // A[m=lane&15][k=quad*8+j]

    float m1[4] = {FLT_MAX, FLT_MAX, FLT_MAX, FLT_MAX};
    for (int nt = 0; nt < N_CODES / 16; ++nt) {
        f32x4 acc = {0.f, 0.f, 0.f, 0.f};
        const ushort_t* bp = eb + (size_t)(nt * 16 + col) * DIM + quad * 8;
        #pragma unroll
        for (int s = 0; s < 8; ++s) {
            const bf16x8 af = *reinterpret_cast<const bf16x8*>(ap + s * 32);
            const bf16x8 bfr = *reinterpret_cast<const bf16x8*>(bp + s * 32);
            acc = __builtin_amdgcn_mfma_f32_16x16x32_bf16(af, bfr, acc, 0, 0, 0);
        }
        const float e2c = e2s[nt * 16 + col];
        #pragma unroll
        for (int r = 0; r < 4; ++r)                     // C/D: col=lane&15, row=quad*4+r
            m1[r] = fminf(m1[r], fmaf(-2.f, acc[r], e2c));
    }
    #pragma unroll
    for (int off = 1; off < 16; off <<= 1)
        #pragma unroll
        for (int r = 0; r < 4; ++r)
            m1[r] = fminf(m1[r], __shfl_xor(m1[r], off));
    if (col == 0)
        #pragma unroll
        for (int r = 0; r < 4; ++r) rmin[wv * 16 + quad * 4 + r] = m1[r];
    __syncthreads();
    float thr[4];
    #pragma unroll
    for (int r = 0; r < 4; ++r) thr[r] = rmin[wv * 16 + quad * 4 + r] + MARGIN;

    for (int nt = 0; nt < N_CODES / 16; ++nt) {         // pass 2: bit-identical recompute
        f32x4 acc = {0.f, 0.f, 0.f, 0.f};
        const ushort_t* bp = eb + (size_t)(nt * 16 + col) * DIM + quad * 8;
        #pragma unroll
        for (int s = 0; s < 8; ++s) {
            const bf16x8 af = *reinterpret_cast<const bf16x8*>(ap + s * 32);
            const bf16x8 bfr = *reinterpret_cast<const bf16x8*>(bp + s * 32);
            acc = __builtin_amdgcn_mfma_f32_16x16x32_bf16(af, bfr, acc, 0, 0, 0);
        }
        const float e2c = e2s[nt * 16 + col];
        #pragma unroll
        for (int r = 0; r < 4; ++r) {
            const float sc = fmaf(-2.f, acc[r], e2c);
            if (sc <= thr[r]) {
                const int n = n0 + wv * 16 + quad * 4 + r;
                const int slot = atomicAdd(&cnt[n], 1);
                if (slot < CAP) cand[(size_t)n * CAP + slot] = nt * 16 + col;
                else if (slot == CAP) {
                    const int o = atomicAdd(ovcount, 1);
                    if (o < 8192) ovlist[o] = n;
                }
            }
        }
    }
}

// np-exact re-resolution of candidates (cnt in [1,CAP]).  Block: 64-pt fp32 z-tile.
__global__ __launch_bounds__(256, 2) void exact_kernel(
    const float* __restrict__ z, const float* __restrict__ emb,
    const float* __restrict__ z2, const float* __restrict__ e2,
    const int* __restrict__ cnt, const int* __restrict__ cand,
    int* __restrict__ idxm, float* __restrict__ out_idx)
{
    __shared__ float zt[64 * 257];
    const int tid = threadIdx.x;
    const int n0 = blockIdx.x * 64;
    const int b = n0 >> 12, s0 = n0 & 4095;
    {
        const int tq = tid & 15, cg = tid >> 4;
        for (int c = cg; c < DIM; c += 16) {
            const float4 u = *reinterpret_cast<const float4*>(
                z + (size_t)b * B_STRIDE + (size_t)c * S_STRIDE + s0 + tq * 4);
            zt[(tq * 4 + 0) * 257 + c] = u.x;
            zt[(tq * 4 + 1) * 257 + c] = u.y;
            zt[(tq * 4 + 2) * 257 + c] = u.z;
            zt[(tq * 4 + 3) * 257 + c] = u.w;
        }
    }
    __syncthreads();
    const int p = tid >> 2, sl = tid & 3;
    const int n = n0 + p;
    const int c0 = cnt[n];
    float sb = FLT_MAX; int kb = 0x7FFFFFFF;
    if (c0 >= 2 && c0 <= CAP) {
        if (sl < c0) {
            const int k = cand[(size_t)n * CAP + sl];
            const float* er = emb + (size_t)k * DIM;
            const float* zr = &zt[p * 257];
            float dot = 0.f;                         // np-exact: ascending-c fmaf chain
            for (int c4 = 0; c4 < 64; ++c4) {
                const float4 ev = reinterpret_cast<const float4*>(er)[c4];
                const float* z4 = zr + c4 * 4;
                dot = fmaf(z4[0], ev.x, dot);
                dot = fmaf(z4[1], ev.y, dot);
                dot = fmaf(z4[2], ev.z, dot);
                dot = fmaf(z4[3], ev.w, dot);
            }
            const float A = __fadd_rn(z2[n], e2[k]);
            sb = __fsub_rn(A, __fmul_rn(2.f, dot));
            kb = k;
        }
        #pragma unroll
        for (int off = 1; off < 4; off <<= 1) {      // lex-min (s, k) across the 4 slots
            const float os = __shfl_xor(sb, off);
            const int ok = __shfl_xor(kb, off);
            if (os < sb || (os == sb && ok < kb)) { sb = os; kb = ok; }
        }
    }
    if (sl == 0) {
        int kf = -1;
        if (c0 == 1) kf = cand[(size_t)n * CAP];
        else if (c0 >= 2 && c0 <= CAP) kf = kb;
        if (kf >= 0) { idxm[n] = kf; out_idx[n] = (float)kf; }
    }
}

// Full np-exact 2048-code scan for rare candidate-overflow points.
__global__ __launch_bounds__(256) void overflow_kernel(
    const float* __restrict__ z, const float* __restrict__ emb,
    const float* __restrict__ z2, const float* __restrict__ e2,
    const int* __restrict__ ovcount, const int* __restrict__ ovlist,
    int* __restrict__ idxm, float* __restrict__ out_idx)
{
    __shared__ float zs[DIM];
    __shared__ float rs[256];
    __shared__ int rk[256];
    const int nov = min(*ovcount, 8192);
    for (int it = blockIdx.x; it < nov; it += gridDim.x) {
        __syncthreads();
        const int n = ovlist[it];
        const int b = n >> 12, s = n & 4095;
        zs[threadIdx.x] = z[(size_t)b * B_STRIDE + (size_t)threadIdx.x * S_STRIDE + s];
        __syncthreads();
        float sb = FLT_MAX; int kb = 0x7FFFFFFF;
        for (int k = threadIdx.x; k < N_CODES; k += 256) {
            const float* er = emb + (size_t)k * DIM;
            float dot = 0.f;
            for (int c4 = 0; c4 < 64; ++c4) {
                const float4 ev = reinterpret_cast<const float4*>(er)[c4];
                dot = fmaf(zs[c4 * 4 + 0], ev.x, dot);
                dot = fmaf(zs[c4 * 4 + 1], ev.y, dot);
                dot = fmaf(zs[c4 * 4 + 2], ev.z, dot);
                dot = fmaf(zs[c4 * 4 + 3], ev.w, dot);
            }
            const float A = __fadd_rn(z2[n], e2[k]);
            const float sc = __fsub_rn(A, __fmul_rn(2.f, dot));
            if (sc < sb || (sc == sb && k < kb)) { sb = sc; kb = k; }
        }
        rs[threadIdx.x] = sb; rk[threadIdx.x] = kb;
        __syncthreads();
        for (int st = 128; st > 0; st >>= 1) {
            if (threadIdx.x < st) {
                const float ov = rs[threadIdx.x + st]; const int ok = rk[threadIdx.x + st];
                if (ov < rs[threadIdx.x] || (ov == rs[threadIdx.x] && ok < rk[threadIdx.x])) {
                    rs[threadIdx.x] = ov; rk[threadIdx.x] = ok;
                }
            }
            __syncthreads();
        }
        if (threadIdx.x == 0) { idxm[n] = rk[0]; out_idx[n] = (float)rk[0]; }
    }
}

// Gather z_q (faithful misaligned reshape), write fp32 z_q_st, fused loss accumulation.
__global__ void gather_loss_kernel(const float* __restrict__ z, const float* __restrict__ emb,
                                   const int* __restrict__ idxm, float* __restrict__ outf,
                                   float* __restrict__ loss)
{
    const int gid = blockIdx.x * 256 + threadIdx.x;
    const size_t m0 = (size_t)gid * 4;
    const int row = (int)(m0 >> 8), col = (int)(m0 & 255);
    const int id = idxm[row];
    const float4 q = *reinterpret_cast<const float4*>(emb + (size_t)id * DIM + col);
    const float4 zv = *reinterpret_cast<const float4*>(z + m0);
    *reinterpret_cast<float4*>(outf + m0) = q;          // z_q_st == z_q in value
    const float d0 = q.x - zv.x, d1 = q.y - zv.y, d2 = q.z - zv.z, d3 = q.w - zv.w;
    float accl = d0 * d0 + d1 * d1 + d2 * d2 + d3 * d3;
    #pragma unroll
    for (int off = 32; off > 0; off >>= 1) accl += __shfl_xor(accl, off);
    __shared__ float part[4];
    const int lane = threadIdx.x & 63, w64 = threadIdx.x >> 6;
    if (lane == 0) part[w64] = accl;
    __syncthreads();
    if (threadIdx.x == 0) atomicAdd(loss, part[0] + part[1] + part[2] + part[3]);
}

__global__ void finalize_kernel(const float* __restrict__ loss, float* __restrict__ out_loss) {
    if (threadIdx.x == 0)
        *out_loss = loss[0] * 1.25f / (float)N_ELEM;     // (1+BETA)*mean
}

extern "C" void kernel_launch(void* const* d_in, const int* in_sizes, int n_in,
                              void* d_out, int out_size, void* d_ws, size_t ws_size,
                              hipStream_t stream) {
    const float* z = (const float*)d_in[0];
    const float* emb = (const float*)d_in[1];
    char* ws = (char*)d_ws;
    float* loss = (float*)(ws + WS_LOSS);
    int* ovcount = (int*)(ws + WS_OVCNT);
    float* e2 = (float*)(ws + WS_E2);
    float* z2 = (float*)(ws + WS_Z2);
    int* idxm = (int*)(ws + WS_IDX);
    ushort_t* eb = (ushort_t*)(ws + WS_EB);
    int* cnt = (int*)(ws + WS_CNT);
    int* cand = (int*)(ws + WS_CAND);
    int* ovlist = (int*)(ws + WS_OV);
    float* outf = (float*)d_out;
    float* out_loss = outf + N_ELEM;
    float* out_idx = outf + N_ELEM + 1;

    init_kernel<<<N_PTS / 256, 256, 0, stream>>>(loss, ovcount, cnt);
    conv_emb_kernel<<<(N_CODES * DIM) / 1024, 256, 0, stream>>>(emb, eb);
    e2_kernel<<<N_CODES / 256, 256, 0, stream>>>(emb, e2);
    z2_kernel<<<N_PTS / 256, 256, 0, stream>>>(z, z2);
    screen_kernel<<<N_PTS / 64, 256, 0, stream>>>(z, eb, e2, cnt, cand, ovlist, ovcount);
    exact_kernel<<<N_PTS / 64, 256, 0, stream>>>(z, emb, z2, e2, cnt, cand, idxm, out_idx);
    overflow_kernel<<<256, 256, 0, stream>>>(z, emb, z2, e2, ovcount, ovlist, idxm, out_idx);
    gather_loss_kernel<<<N_ELEM / 1024, 256, 0, stream>>>(z, emb, idxm, outf, loss);
    finalize_kernel<<<1, 64, 0, stream>>>(loss, out_loss);
}

// Round 6
// 499.926 us; speedup vs baseline: 1.5071x; 1.5071x over previous
//
#include <hip/hip_runtime.h>
#include <float.h>

// Problem constants
#define N_PTS    32768       // 8*16*16*16 spatial positions
#define N_CODES  2048
#define DIM      256
#define S_STRIDE 4096        // d*h*w stride of channel dim in z (floats)
#define B_STRIDE 1048576     // per-batch stride in z (256*4096 floats)
#define N_ELEM   8388608     // total z elements

#define MARGIN   8e-4f       // >= 2x |screen-score - np-score| bound (~2.3e-4)
#define PITCH    264         // bf16 row pitch (264*2=528 B): linear-copy friendly, banks ~2-way

// ws layout (bytes), 16-aligned
#define WS_LOSS   0          // float
#define WS_E2     16         // float[2048]                      -> 8208
#define WS_Z2     8208       // float[32768]                     -> 139280
#define WS_IDX    139280     // int[32768]                       -> 270352
#define WS_EB     270352     // bf16[2048*264]                   -> 1351696
#define WS_ZT     1351696    // bf16[32768*264]                  -> 18653200
#define WS_TMIN   18653200   // float[32768*128]                 -> 35430416

typedef unsigned short ushort_t;
typedef short bf16x8 __attribute__((ext_vector_type(8)));
typedef float f32x4 __attribute__((ext_vector_type(4)));

__device__ __forceinline__ ushort_t f2bf(float v) {   // RNE fp32->bf16 (no NaN in data)
    const unsigned u = __float_as_uint(v);
    return (ushort_t)((u + 0x7FFFu + ((u >> 16) & 1u)) >> 16);
}

__device__ __forceinline__ void async_copy16(void* lds, const void* g) {
    __builtin_amdgcn_global_load_lds(
        (const __attribute__((address_space(1))) unsigned int*)g,
        (__attribute__((address_space(3))) unsigned int*)lds, 16, 0, 0);
}

__global__ void init_kernel(float* loss) {
    if (threadIdx.x == 0) *loss = 0.f;
}

// emb fp32 [k][256] -> bf16 eb [k][PITCH]
__global__ void conv_emb_kernel(const float* __restrict__ emb, ushort_t* __restrict__ eb) {
    const int gid = blockIdx.x * 256 + threadIdx.x;   // 512 blocks: 2048 codes x 64 float4
    const int k = gid >> 6, c4 = gid & 63;
    const float4 u = *reinterpret_cast<const float4*>(emb + (size_t)k * DIM + c4 * 4);
    ushort4 v; v.x = f2bf(u.x); v.y = f2bf(u.y); v.z = f2bf(u.z); v.w = f2bf(u.w);
    *reinterpret_cast<ushort4*>(eb + (size_t)k * PITCH + c4 * 4) = v;
}

// z [8][256][4096] fp32 -> z_t [n=b*4096+s][c] bf16 (pitch PITCH), 64x64 LDS transpose tiles.
__global__ void transpose_kernel(const float* __restrict__ z, ushort_t* __restrict__ zt) {
    __shared__ ushort_t lt[64][72];
    const int bx = blockIdx.x;            // 2048 = 8 b x 4 cg x 64 sg
    const int b = bx >> 8, cg = (bx >> 6) & 3, sg = bx & 63;
    const int c0 = cg * 64, s0 = sg * 64;
    const int t = threadIdx.x;
    {
        const int cl = t >> 4, s4 = t & 15;
        #pragma unroll
        for (int j = 0; j < 4; ++j) {
            const int c = cl + 16 * j;
            const float4 u = *reinterpret_cast<const float4*>(
                z + (size_t)b * B_STRIDE + (size_t)(c0 + c) * S_STRIDE + s0 + s4 * 4);
            ushort4 v; v.x = f2bf(u.x); v.y = f2bf(u.y); v.z = f2bf(u.z); v.w = f2bf(u.w);
            *reinterpret_cast<ushort4*>(&lt[c][s4 * 4]) = v;
        }
    }
    __syncthreads();
    {
        const int sl = t >> 4, c4 = t & 15;
        #pragma unroll
        for (int j = 0; j < 4; ++j) {
            const int s = sl + 16 * j;
            ushort4 v;
            v.x = lt[c4 * 4 + 0][s]; v.y = lt[c4 * 4 + 1][s];
            v.z = lt[c4 * 4 + 2][s]; v.w = lt[c4 * 4 + 3][s];
            *reinterpret_cast<ushort4*>(zt + (size_t)(b * 4096 + s0 + s) * PITCH + c0 + c4 * 4) = v;
        }
    }
}

// numpy pairwise-sum emulation (n=256): two 128-blocks of 8 accumulators.
__global__ void e2_kernel(const float* __restrict__ emb, float* __restrict__ e2) {
    const int k = blockIdx.x * 256 + threadIdx.x;
    const float* base = emb + (size_t)k * DIM;
    float half[2];
    #pragma unroll
    for (int h = 0; h < 2; ++h) {
        float r[8];
        #pragma unroll
        for (int j = 0; j < 8; ++j) { const float v = base[h * 128 + j]; r[j] = __fmul_rn(v, v); }
        for (int t = 8; t < 128; t += 8)
            #pragma unroll
            for (int j = 0; j < 8; ++j) {
                const float v = base[h * 128 + t + j];
                r[j] = __fadd_rn(r[j], __fmul_rn(v, v));
            }
        half[h] = __fadd_rn(__fadd_rn(__fadd_rn(r[0], r[1]), __fadd_rn(r[2], r[3])),
                            __fadd_rn(__fadd_rn(r[4], r[5]), __fadd_rn(r[6], r[7])));
    }
    e2[k] = __fadd_rn(half[0], half[1]);
}

__global__ void z2_kernel(const float* __restrict__ z, float* __restrict__ z2) {
    const int n = blockIdx.x * 256 + threadIdx.x;
    const int b = n >> 12, s = n & 4095;
    const float* base = z + (size_t)b * B_STRIDE + s;
    float half[2];
    #pragma unroll
    for (int h = 0; h < 2; ++h) {
        float r[8];
        #pragma unroll
        for (int j = 0; j < 8; ++j) {
            const float v = base[(size_t)(h * 128 + j) * S_STRIDE];
            r[j] = __fmul_rn(v, v);
        }
        for (int t = 8; t < 128; t += 8)
            #pragma unroll
            for (int j = 0; j < 8; ++j) {
                const float v = base[(size_t)(h * 128 + t + j) * S_STRIDE];
                r[j] = __fadd_rn(r[j], __fmul_rn(v, v));
            }
        half[h] = __fadd_rn(__fadd_rn(__fadd_rn(r[0], r[1]), __fadd_rn(r[2], r[3])),
                            __fadd_rn(__fadd_rn(r[4], r[5]), __fadd_rn(r[6], r[7])));
    }
    z2[n] = __fadd_rn(half[0], half[1]);
}

// Single-pass bf16 MFMA screen GEMM: 128 pts x 128 codes per block, K=256.
// Emits per-(point, 16-code-group) minima of s~ = e2[k] - 2*dot_bf16.
__global__ __launch_bounds__(256, 1) void screen_kernel(
    const ushort_t* __restrict__ zt, const ushort_t* __restrict__ eb,
    const float* __restrict__ e2, float* __restrict__ tmin)
{
    __shared__ ushort_t lA[128 * PITCH];   // 66 KB
    __shared__ ushort_t lB[128 * PITCH];   // 66 KB
    __shared__ float e2s[128];
    const int tid = threadIdx.x;
    const int bm = blockIdx.x & 255, bn = blockIdx.x >> 8;   // bm fast -> eb tile L2-resident
    const int n0 = bm * 128, k0 = bn * 128;
    if (tid < 128) e2s[tid] = e2[k0 + tid];
    const ushort_t* gA = zt + (size_t)n0 * PITCH;   // contiguous 128*528 B region
    const ushort_t* gB = eb + (size_t)k0 * PITCH;
    for (int c = tid; c < 4224; c += 256)           // 128*528/16 = 4224 chunks
        async_copy16((char*)lA + c * 16, (const char*)gA + c * 16);
    for (int c = tid; c < 4224; c += 256)
        async_copy16((char*)lB + c * 16, (const char*)gB + c * 16);
    __syncthreads();

    const int lane = tid & 63, wv = tid >> 6;
    const int col = lane & 15, quad = lane >> 4;
    const int roff = (wv >> 1) * 64, coff = (wv & 1) * 64;   // wave's 64x64 quadrant
    f32x4 acc[4][4];
    #pragma unroll
    for (int i = 0; i < 4; ++i)
        #pragma unroll
        for (int j = 0; j < 4; ++j) acc[i][j] = (f32x4){0.f, 0.f, 0.f, 0.f};

    const ushort_t* Ab = &lA[(roff + col) * PITCH + quad * 8];
    const ushort_t* Bb = &lB[(coff + col) * PITCH + quad * 8];
    #pragma unroll
    for (int s = 0; s < 8; ++s) {                    // K = 8 x 32
        bf16x8 af[4], bq[4];
        #pragma unroll
        for (int i = 0; i < 4; ++i)
            af[i] = *reinterpret_cast<const bf16x8*>(Ab + i * 16 * PITCH + s * 32);
        #pragma unroll
        for (int j = 0; j < 4; ++j)
            bq[j] = *reinterpret_cast<const bf16x8*>(Bb + j * 16 * PITCH + s * 32);
        #pragma unroll
        for (int i = 0; i < 4; ++i)
            #pragma unroll
            for (int j = 0; j < 4; ++j)
                acc[i][j] = __builtin_amdgcn_mfma_f32_16x16x32_bf16(af[i], bq[j], acc[i][j], 0, 0, 0);
    }

    // epilogue: s~ = e2 - 2*dot; per-16-code-group min (reduce across col lanes)
    #pragma unroll
    for (int j = 0; j < 4; ++j) {
        const float e2v = e2s[coff + j * 16 + col];
        const int ct = bn * 8 + (coff >> 4) + j;
        #pragma unroll
        for (int i = 0; i < 4; ++i) {
            float tm[4];
            #pragma unroll
            for (int r = 0; r < 4; ++r) tm[r] = fmaf(-2.f, acc[i][j][r], e2v);
            #pragma unroll
            for (int off = 1; off < 16; off <<= 1)
                #pragma unroll
                for (int r = 0; r < 4; ++r) tm[r] = fminf(tm[r], __shfl_xor(tm[r], off));
            if (col == 0) {
                const int nb = n0 + roff + i * 16 + quad * 4;   // C/D row = quad*4+r
                #pragma unroll
                for (int r = 0; r < 4; ++r) tmin[(size_t)(nb + r) * 128 + ct] = tm[r];
            }
        }
    }
}

// Per point: select groups within MARGIN of the screen min; np-exact re-score those
// codes (ascending-c fmaf chain + fl(fl(z2+e2)-2dot)), lex-min (s,k) = np.argmin.
__global__ __launch_bounds__(256) void exact_kernel(
    const float* __restrict__ z, const float* __restrict__ emb,
    const float* __restrict__ z2, const float* __restrict__ e2,
    const float* __restrict__ tmin, int* __restrict__ idxm, float* __restrict__ out_idx)
{
    __shared__ float zs[4][257];
    const int tid = threadIdx.x;
    const int n0 = blockIdx.x * 4;
    {   // stage 4 points' fp32 z rows
        const int p = tid & 3, c = tid >> 2;   // c in [0,64)
        const int n = n0 + p, b = n >> 12, s = n & 4095;
        const float* zb = z + (size_t)b * B_STRIDE + s;
        #pragma unroll
        for (int j = 0; j < 4; ++j)
            zs[p][c + 64 * j] = zb[(size_t)(c + 64 * j) * S_STRIDE];
    }
    __syncthreads();
    const int wv = tid >> 6, lane = tid & 63;
    const int n = n0 + wv;
    const float a0 = tmin[(size_t)n * 128 + lane];
    const float a1 = tmin[(size_t)n * 128 + 64 + lane];
    float mn = fminf(a0, a1);
    #pragma unroll
    for (int off = 1; off < 64; off <<= 1) mn = fminf(mn, __shfl_xor(mn, off));
    const float thr = mn + MARGIN;
    unsigned long long M0 = __ballot(a0 <= thr);
    unsigned long long M1 = __ballot(a1 <= thr);
    const float z2n = z2[n];
    float bs = FLT_MAX; int bk = 0x7FFFFFFF;
    while (M0 | M1) {
        int sel[4];
        #pragma unroll
        for (int sl = 0; sl < 4; ++sl) {          // wave-uniform extraction of <=4 groups
            int v = -1;
            if (M0) { v = __ffsll((unsigned long long)M0) - 1; M0 &= M0 - 1; }
            else if (M1) { v = 64 + __ffsll((unsigned long long)M1) - 1; M1 &= M1 - 1; }
            sel[sl] = v;
        }
        const int myt = sel[lane >> 4];
        if (myt >= 0) {
            const int kg = myt * 16 + (lane & 15);
            const float* er = emb + (size_t)kg * DIM;
            const float* zr = zs[wv];
            float dot = 0.f;                       // np-exact ascending-c fmaf chain
            for (int c4 = 0; c4 < 64; ++c4) {
                const float4 ev = reinterpret_cast<const float4*>(er)[c4];
                dot = fmaf(zr[c4 * 4 + 0], ev.x, dot);
                dot = fmaf(zr[c4 * 4 + 1], ev.y, dot);
                dot = fmaf(zr[c4 * 4 + 2], ev.z, dot);
                dot = fmaf(zr[c4 * 4 + 3], ev.w, dot);
            }
            const float A = __fadd_rn(z2n, e2[kg]);
            const float s = __fsub_rn(A, __fmul_rn(2.f, dot));
            if (s < bs || (s == bs && kg < bk)) { bs = s; bk = kg; }
        }
    }
    #pragma unroll
    for (int off = 1; off < 64; off <<= 1) {
        const float os = __shfl_xor(bs, off);
        const int ok = __shfl_xor(bk, off);
        if (os < bs || (os == bs && ok < bk)) { bs = os; bk = ok; }
    }
    if (lane == 0) { idxm[n] = bk; out_idx[n] = (float)bk; }
}

// Gather z_q (faithful misaligned reshape), write fp32 z_q_st, fused loss accumulation.
__global__ void gather_loss_kernel(const float* __restrict__ z, const float* __restrict__ emb,
                                   const int* __restrict__ idxm, float* __restrict__ outf,
                                   float* __restrict__ loss)
{
    const int gid = blockIdx.x * 256 + threadIdx.x;
    const size_t m0 = (size_t)gid * 4;
    const int row = (int)(m0 >> 8), col = (int)(m0 & 255);
    const int id = idxm[row];
    const float4 q = *reinterpret_cast<const float4*>(emb + (size_t)id * DIM + col);
    const float4 zv = *reinterpret_cast<const float4*>(z + m0);
    *reinterpret_cast<float4*>(outf + m0) = q;          // z_q_st == z_q in value
    const float d0 = q.x - zv.x, d1 = q.y - zv.y, d2 = q.z - zv.z, d3 = q.w - zv.w;
    float accl = d0 * d0 + d1 * d1 + d2 * d2 + d3 * d3;
    #pragma unroll
    for (int off = 32; off > 0; off >>= 1) accl += __shfl_xor(accl, off);
    __shared__ float part[4];
    const int lane = threadIdx.x & 63, w64 = threadIdx.x >> 6;
    if (lane == 0) part[w64] = accl;
    __syncthreads();
    if (threadIdx.x == 0) atomicAdd(loss, part[0] + part[1] + part[2] + part[3]);
}

__global__ void finalize_kernel(const float* __restrict__ loss, float* __restrict__ out_loss) {
    if (threadIdx.x == 0)
        *out_loss = loss[0] * 1.25f / (float)N_ELEM;     // (1+BETA)*mean
}

extern "C" void kernel_launch(void* const* d_in, const int* in_sizes, int n_in,
                              void* d_out, int out_size, void* d_ws, size_t ws_size,
                              hipStream_t stream) {
    const float* z = (const float*)d_in[0];
    const float* emb = (const float*)d_in[1];
    char* ws = (char*)d_ws;
    float* loss = (float*)(ws + WS_LOSS);
    float* e2 = (float*)(ws + WS_E2);
    float* z2 = (float*)(ws + WS_Z2);
    int* idxm = (int*)(ws + WS_IDX);
    ushort_t* eb = (ushort_t*)(ws + WS_EB);
    ushort_t* zt = (ushort_t*)(ws + WS_ZT);
    float* tmin = (float*)(ws + WS_TMIN);
    float* outf = (float*)d_out;
    float* out_loss = outf + N_ELEM;
    float* out_idx = outf + N_ELEM + 1;

    init_kernel<<<1, 64, 0, stream>>>(loss);
    conv_emb_kernel<<<512, 256, 0, stream>>>(emb, eb);
    transpose_kernel<<<2048, 256, 0, stream>>>(z, zt);
    e2_kernel<<<N_CODES / 256, 256, 0, stream>>>(emb, e2);
    z2_kernel<<<N_PTS / 256, 256, 0, stream>>>(z, z2);
    screen_kernel<<<4096, 256, 0, stream>>>(zt, eb, e2, tmin);
    exact_kernel<<<N_PTS / 4, 256, 0, stream>>>(z, emb, z2, e2, tmin, idxm, out_idx);
    gather_loss_kernel<<<N_ELEM / 1024, 256, 0, stream>>>(z, emb, idxm, outf, loss);
    finalize_kernel<<<1, 64, 0, stream>>>(loss, out_loss);
}

// Round 7
// 486.731 us; speedup vs baseline: 1.5479x; 1.0271x over previous
//
#include <hip/hip_runtime.h>
#include <float.h>

// Problem constants
#define N_PTS    32768       // 8*16*16*16 spatial positions
#define N_CODES  2048
#define DIM      256
#define S_STRIDE 4096        // d*h*w stride of channel dim in z (floats)
#define B_STRIDE 1048576     // per-batch stride in z (256*4096 floats)
#define N_ELEM   8388608     // total z elements

#define MARGIN   8e-4f       // >= 2x |screen-score - np-score| bound (validated R5/R6)

// ws layout (bytes), 512-aligned
#define WS_PARTIAL 0          // float[64]
#define WS_E2      512        // float[2048]            -> 8704
#define WS_EB      8704       // bf16[2048*256] 1 MB    -> 1057280
#define WS_ZT      1057280    // bf16[32768*256] 16.8MB -> 17834496
#define WS_TMIN    17834496   // float[32768*32] 4 MB   -> 22028800

typedef unsigned short ushort_t;
typedef short bf16x8 __attribute__((ext_vector_type(8)));
typedef float f32x4 __attribute__((ext_vector_type(4)));

__device__ __forceinline__ ushort_t f2bf(float v) {   // RNE fp32->bf16 (no NaN in data)
    const unsigned u = __float_as_uint(v);
    return (ushort_t)((u + 0x7FFFu + ((u >> 16) & 1u)) >> 16);
}

__device__ __forceinline__ void async_copy16(void* lds, const void* g) {
    __builtin_amdgcn_global_load_lds(
        (const __attribute__((address_space(1))) unsigned int*)g,
        (__attribute__((address_space(3))) unsigned int*)lds, 16, 0, 0);
}

// emb fp32 [k][256] -> bf16 eb [k][256] (coalesced)
__global__ void conv_emb_kernel(const float* __restrict__ emb, ushort_t* __restrict__ eb) {
    const int gid = blockIdx.x * 256 + threadIdx.x;   // 512 blocks: 2048 codes x 64 float4
    const int k = gid >> 6, c4 = gid & 63;
    const float4 u = *reinterpret_cast<const float4*>(emb + (size_t)k * DIM + c4 * 4);
    ushort4 v; v.x = f2bf(u.x); v.y = f2bf(u.y); v.z = f2bf(u.z); v.w = f2bf(u.w);
    *reinterpret_cast<ushort4*>(eb + (size_t)k * DIM + c4 * 4) = v;
}

// e2[k] = np-pairwise sum of emb[k][:]^2; also zeroes loss partials.
__global__ void e2p_kernel(const float* __restrict__ emb, float* __restrict__ e2,
                           float* __restrict__ partial) {
    const int k = blockIdx.x * 256 + threadIdx.x;
    if (blockIdx.x == 0 && threadIdx.x < 64) partial[threadIdx.x] = 0.f;
    const float* base = emb + (size_t)k * DIM;
    float half[2];
    #pragma unroll
    for (int h = 0; h < 2; ++h) {
        float r[8];
        #pragma unroll
        for (int j = 0; j < 8; ++j) { const float v = base[h * 128 + j]; r[j] = __fmul_rn(v, v); }
        for (int t = 8; t < 128; t += 8)
            #pragma unroll
            for (int j = 0; j < 8; ++j) {
                const float v = base[h * 128 + t + j];
                r[j] = __fadd_rn(r[j], __fmul_rn(v, v));
            }
        half[h] = __fadd_rn(__fadd_rn(__fadd_rn(r[0], r[1]), __fadd_rn(r[2], r[3])),
                            __fadd_rn(__fadd_rn(r[4], r[5]), __fadd_rn(r[6], r[7])));
    }
    e2[k] = __fadd_rn(half[0], half[1]);
}

// z [8][256][4096] fp32 -> z_t [n][c] bf16 (pitch 256), 64x64 LDS transpose tiles.
__global__ void transpose_kernel(const float* __restrict__ z, ushort_t* __restrict__ zt) {
    __shared__ ushort_t lt[64][72];
    const int bx = blockIdx.x;            // 2048 = 8 b x 4 cg x 64 sg
    const int b = bx >> 8, cg = (bx >> 6) & 3, sg = bx & 63;
    const int c0 = cg * 64, s0 = sg * 64;
    const int t = threadIdx.x;
    {
        const int cl = t >> 4, s4 = t & 15;
        #pragma unroll
        for (int j = 0; j < 4; ++j) {
            const int c = cl + 16 * j;
            const float4 u = *reinterpret_cast<const float4*>(
                z + (size_t)b * B_STRIDE + (size_t)(c0 + c) * S_STRIDE + s0 + s4 * 4);
            ushort4 v; v.x = f2bf(u.x); v.y = f2bf(u.y); v.z = f2bf(u.z); v.w = f2bf(u.w);
            *reinterpret_cast<ushort4*>(&lt[c][s4 * 4]) = v;
        }
    }
    __syncthreads();
    {
        const int sl = t >> 4, c4 = t & 15;
        #pragma unroll
        for (int j = 0; j < 4; ++j) {
            const int s = sl + 16 * j;
            ushort4 v;
            v.x = lt[c4 * 4 + 0][s]; v.y = lt[c4 * 4 + 1][s];
            v.z = lt[c4 * 4 + 2][s]; v.w = lt[c4 * 4 + 3][s];
            *reinterpret_cast<ushort4*>(zt + (size_t)(b * 4096 + s0 + s) * DIM + c0 + c4 * 4) = v;
        }
    }
}

// m97-style screen GEMM: BM=128 pts, BN=256 codes, BK=64, single 48 KB buffer,
// 2-barrier K-loop, global_load_lds staging with XOR chunk swizzle, 8x4 wave tile.
// Emits per-(point, 64-code-group) min of s~ = e2[k] - 2*dot_bf16 -> tmin[n][32].
__global__ __launch_bounds__(256, 2) void screen_kernel(
    const ushort_t* __restrict__ zt, const ushort_t* __restrict__ eb,
    const float* __restrict__ e2, float* __restrict__ tmin)
{
    __shared__ char lds[49152];          // A: [0,16K) = 128 rows x 8 chunks; B: [16K,48K) = 256 x 8
    __shared__ float e2s[256];
    const int tid = threadIdx.x;
    const int bm = blockIdx.x & 255, bn = blockIdx.x >> 8;   // bm fast -> eb tile L2-hot
    const int n0 = bm * 128, k0 = bn * 256;
    e2s[tid] = e2[k0 + tid];
    const int wv = tid >> 6, lane = tid & 63;
    const int col = lane & 15, quad = lane >> 4;
    const int cswz = col & 7;

    f32x4 acc[8][4];
    #pragma unroll
    for (int i = 0; i < 8; ++i)
        #pragma unroll
        for (int j = 0; j < 4; ++j) acc[i][j] = (f32x4){0.f, 0.f, 0.f, 0.f};

    for (int kc = 0; kc < 4; ++kc) {
        __syncthreads();                 // prior-iter LDS reads done before overwrite
        #pragma unroll
        for (int it = 0; it < 12; ++it) {    // 3072 x 16B chunks: A 1024, B 2048
            const int L = tid + it * 256;
            if (L < 1024) {
                const int row = L >> 3, pc = L & 7, c = pc ^ (row & 7);
                async_copy16(lds + L * 16,
                             zt + ((size_t)(n0 + row) * DIM + kc * 64 + c * 8));
            } else {
                const int L2 = L - 1024;
                const int row = L2 >> 3, pc = L2 & 7, c = pc ^ (row & 7);
                async_copy16(lds + 16384 + L2 * 16,
                             eb + ((size_t)(k0 + row) * DIM + kc * 64 + c * 8));
            }
        }
        __syncthreads();                 // drains vmcnt: staged data visible
        #pragma unroll
        for (int s = 0; s < 2; ++s) {
            const int pc = (s * 4 + quad) ^ cswz;
            bf16x8 bq[4];
            #pragma unroll
            for (int j = 0; j < 4; ++j) {
                const int brow = wv * 64 + j * 16 + col;
                bq[j] = *reinterpret_cast<const bf16x8*>(lds + 16384 + (brow * 8 + pc) * 16);
            }
            #pragma unroll
            for (int i = 0; i < 8; ++i) {
                const int arow = i * 16 + col;
                const bf16x8 af = *reinterpret_cast<const bf16x8*>(lds + (arow * 8 + pc) * 16);
                #pragma unroll
                for (int j = 0; j < 4; ++j)
                    acc[i][j] = __builtin_amdgcn_mfma_f32_16x16x32_bf16(af, bq[j], acc[i][j], 0, 0, 0);
            }
        }
    }
    // epilogue: per point, min over this wave's 64 codes (one 64-group per wave)
    #pragma unroll
    for (int i = 0; i < 8; ++i) {
        float tm[4];
        #pragma unroll
        for (int r = 0; r < 4; ++r) {
            float m = fmaf(-2.f, acc[i][0][r], e2s[wv * 64 + col]);
            #pragma unroll
            for (int j = 1; j < 4; ++j)
                m = fminf(m, fmaf(-2.f, acc[i][j][r], e2s[wv * 64 + j * 16 + col]));
            tm[r] = m;
        }
        #pragma unroll
        for (int off = 1; off < 16; off <<= 1)
            #pragma unroll
            for (int r = 0; r < 4; ++r) tm[r] = fminf(tm[r], __shfl_xor(tm[r], off));
        if (col == 0) {
            #pragma unroll
            for (int r = 0; r < 4; ++r)
                tmin[(size_t)(n0 + i * 16 + quad * 4 + r) * 32 + bn * 4 + wv] = tm[r];
        }
    }
}

// Fused exact re-resolve + z2 + gather + loss.  Block: 4 points (one per wave).
__global__ __launch_bounds__(256) void exact_kernel(
    const float* __restrict__ z, const float* __restrict__ emb,
    const float* __restrict__ e2, const float* __restrict__ tmin,
    float* __restrict__ outf, float* __restrict__ out_idx, float* __restrict__ partial)
{
    __shared__ float zs[4][260];
    __shared__ float lpart[4];
    const int tid = threadIdx.x;
    const int n0 = blockIdx.x * 4;
    {   // stage 4 fp32 z rows
        const int p = tid & 3, c = tid >> 2;   // c in [0,64)
        const int nn = n0 + p, b = nn >> 12, s = nn & 4095;
        const float* zb = z + (size_t)b * B_STRIDE + s;
        #pragma unroll
        for (int j = 0; j < 4; ++j)
            zs[p][c + 64 * j] = zb[(size_t)(c + 64 * j) * S_STRIDE];
    }
    __syncthreads();
    const int wv = tid >> 6, lane = tid & 63;
    const int n = n0 + wv;
    // np-exact z2: 16 lanes run the 8-accumulator chains, xor-tree combine in np order
    float r = 0.f;
    if (lane < 16) {
        const int h = lane >> 3, j = lane & 7;
        const float* zr = &zs[wv][h * 128 + j];
        float v = zr[0];
        r = __fmul_rn(v, v);
        #pragma unroll
        for (int t = 1; t < 16; ++t) { v = zr[t * 8]; r = __fadd_rn(r, __fmul_rn(v, v)); }
    }
    { float v = __shfl_xor(r, 1); r = __fadd_rn(r, v); }   // (r0+r1),(r2+r3),...
    { float v = __shfl_xor(r, 2); r = __fadd_rn(r, v); }   // (r01+r23),(r45+r67)
    { float v = __shfl_xor(r, 4); r = __fadd_rn(r, v); }   // half sums at lanes 0,8
    const float z2n = __fadd_rn(__shfl(r, 0), __shfl(r, 8));
    // threshold over 32 group minima
    float a = FLT_MAX;
    if (lane < 32) a = tmin[(size_t)n * 32 + lane];
    float mn = a;
    #pragma unroll
    for (int off = 1; off < 64; off <<= 1) mn = fminf(mn, __shfl_xor(mn, off));
    const float thr = mn + MARGIN;
    unsigned long long mask = __ballot(a <= thr);
    float bs = FLT_MAX; int bk = 0x7FFFFFFF;
    while (mask) {
        const int g = __ffsll(mask) - 1; mask &= mask - 1;
        const int k = g * 64 + lane;
        const float* er = emb + (size_t)k * DIM;
        const float* zr = zs[wv];
        float dot = 0.f;                       // np-exact ascending-c fmaf chain
        #pragma unroll 8
        for (int c4 = 0; c4 < 64; ++c4) {
            const float4 ev = reinterpret_cast<const float4*>(er)[c4];
            dot = fmaf(zr[c4 * 4 + 0], ev.x, dot);
            dot = fmaf(zr[c4 * 4 + 1], ev.y, dot);
            dot = fmaf(zr[c4 * 4 + 2], ev.z, dot);
            dot = fmaf(zr[c4 * 4 + 3], ev.w, dot);
        }
        const float A = __fadd_rn(z2n, e2[k]);
        const float s = __fsub_rn(A, __fmul_rn(2.f, dot));
        if (s < bs || (s == bs && k < bk)) { bs = s; bk = k; }
    }
    #pragma unroll
    for (int off = 1; off < 64; off <<= 1) {   // lex-min (s,k) = np.argmin
        const float os = __shfl_xor(bs, off);
        const int ok = __shfl_xor(bk, off);
        if (os < bs || (os == bs && ok < bk)) { bs = os; bk = ok; }
    }
    // gather z_q row (faithful misaligned reshape: out[n][c] = emb[idx[n]][c]) + loss
    const float4 q = reinterpret_cast<const float4*>(emb + (size_t)bk * DIM)[lane];
    reinterpret_cast<float4*>(outf + (size_t)n * DIM)[lane] = q;
    const float* zr = zs[wv];
    const float d0 = q.x - zr[lane * 4 + 0], d1 = q.y - zr[lane * 4 + 1];
    const float d2 = q.z - zr[lane * 4 + 2], d3 = q.w - zr[lane * 4 + 3];
    float l = d0 * d0 + d1 * d1 + d2 * d2 + d3 * d3;
    #pragma unroll
    for (int off = 1; off < 64; off <<= 1) l += __shfl_xor(l, off);
    if (lane == 0) { out_idx[n] = (float)bk; lpart[wv] = l; }
    __syncthreads();
    if (tid == 0)
        atomicAdd(&partial[blockIdx.x & 63], lpart[0] + lpart[1] + lpart[2] + lpart[3]);
}

__global__ void finalize_kernel(const float* __restrict__ partial, float* __restrict__ out_loss) {
    float v = partial[threadIdx.x];          // 64 threads
    #pragma unroll
    for (int off = 1; off < 64; off <<= 1) v += __shfl_xor(v, off);
    if (threadIdx.x == 0)
        *out_loss = v * 1.25f / (float)N_ELEM;   // (1+BETA)*mean
}

extern "C" void kernel_launch(void* const* d_in, const int* in_sizes, int n_in,
                              void* d_out, int out_size, void* d_ws, size_t ws_size,
                              hipStream_t stream) {
    const float* z = (const float*)d_in[0];
    const float* emb = (const float*)d_in[1];
    char* ws = (char*)d_ws;
    float* partial = (float*)(ws + WS_PARTIAL);
    float* e2 = (float*)(ws + WS_E2);
    ushort_t* eb = (ushort_t*)(ws + WS_EB);
    ushort_t* zt = (ushort_t*)(ws + WS_ZT);
    float* tmin = (float*)(ws + WS_TMIN);
    float* outf = (float*)d_out;
    float* out_loss = outf + N_ELEM;
    float* out_idx = outf + N_ELEM + 1;

    conv_emb_kernel<<<512, 256, 0, stream>>>(emb, eb);
    e2p_kernel<<<N_CODES / 256, 256, 0, stream>>>(emb, e2, partial);
    transpose_kernel<<<2048, 256, 0, stream>>>(z, zt);
    screen_kernel<<<2048, 256, 0, stream>>>(zt, eb, e2, tmin);
    exact_kernel<<<N_PTS / 4, 256, 0, stream>>>(z, emb, e2, tmin, outf, out_idx, partial);
    finalize_kernel<<<1, 64, 0, stream>>>(partial, out_loss);
}

// Round 8
// 315.507 us; speedup vs baseline: 2.3880x; 1.5427x over previous
//
#include <hip/hip_runtime.h>
#include <float.h>

// Problem constants
#define N_PTS    32768       // 8*16*16*16 spatial positions
#define N_CODES  2048
#define DIM      256
#define S_STRIDE 4096        // d*h*w stride of channel dim in z (floats)
#define B_STRIDE 1048576     // per-batch stride in z (256*4096 floats)
#define N_ELEM   8388608     // total z elements

#define MARGIN   8e-4f       // >= 2x |screen-score - np-score| bound (validated R5-R7)

// ws layout (bytes), 512-aligned
#define WS_PARTIAL 0          // float[64]
#define WS_E2      512        // float[2048]             -> 8704
#define WS_EB      8704       // bf16[2048*256] 1 MB     -> 1057280
#define WS_ZT      1057280    // bf16[32768*256] 16.8 MB -> 17834496
#define WS_TMIN    17834496   // float[32768*128] 16.8MB -> 34611712

typedef unsigned short ushort_t;
typedef short bf16x8 __attribute__((ext_vector_type(8)));
typedef float f32x4 __attribute__((ext_vector_type(4)));

__device__ __forceinline__ ushort_t f2bf(float v) {   // RNE fp32->bf16 (no NaN in data)
    const unsigned u = __float_as_uint(v);
    return (ushort_t)((u + 0x7FFFu + ((u >> 16) & 1u)) >> 16);
}

__device__ __forceinline__ void async_copy16(void* lds, const void* g) {
    __builtin_amdgcn_global_load_lds(
        (const __attribute__((address_space(1))) unsigned int*)g,
        (__attribute__((address_space(3))) unsigned int*)lds, 16, 0, 0);
}

// emb fp32 [k][256] -> bf16 eb [k][256] (coalesced)
__global__ void conv_emb_kernel(const float* __restrict__ emb, ushort_t* __restrict__ eb) {
    const int gid = blockIdx.x * 256 + threadIdx.x;   // 512 blocks: 2048 codes x 64 float4
    const int k = gid >> 6, c4 = gid & 63;
    const float4 u = *reinterpret_cast<const float4*>(emb + (size_t)k * DIM + c4 * 4);
    ushort4 v; v.x = f2bf(u.x); v.y = f2bf(u.y); v.z = f2bf(u.z); v.w = f2bf(u.w);
    *reinterpret_cast<ushort4*>(eb + (size_t)k * DIM + c4 * 4) = v;
}

// e2[k] = np-pairwise sum of emb[k][:]^2; also zeroes loss partials.
__global__ void e2p_kernel(const float* __restrict__ emb, float* __restrict__ e2,
                           float* __restrict__ partial) {
    const int k = blockIdx.x * 256 + threadIdx.x;
    if (blockIdx.x == 0 && threadIdx.x < 64) partial[threadIdx.x] = 0.f;
    const float* base = emb + (size_t)k * DIM;
    float half[2];
    #pragma unroll
    for (int h = 0; h < 2; ++h) {
        float r[8];
        #pragma unroll
        for (int j = 0; j < 8; ++j) { const float v = base[h * 128 + j]; r[j] = __fmul_rn(v, v); }
        for (int t = 8; t < 128; t += 8)
            #pragma unroll
            for (int j = 0; j < 8; ++j) {
                const float v = base[h * 128 + t + j];
                r[j] = __fadd_rn(r[j], __fmul_rn(v, v));
            }
        half[h] = __fadd_rn(__fadd_rn(__fadd_rn(r[0], r[1]), __fadd_rn(r[2], r[3])),
                            __fadd_rn(__fadd_rn(r[4], r[5]), __fadd_rn(r[6], r[7])));
    }
    e2[k] = __fadd_rn(half[0], half[1]);
}

// z [8][256][4096] fp32 -> z_t [n][c] bf16 (pitch 256), 64x64 LDS transpose tiles.
__global__ void transpose_kernel(const float* __restrict__ z, ushort_t* __restrict__ zt) {
    __shared__ ushort_t lt[64][72];
    const int bx = blockIdx.x;            // 2048 = 8 b x 4 cg x 64 sg
    const int b = bx >> 8, cg = (bx >> 6) & 3, sg = bx & 63;
    const int c0 = cg * 64, s0 = sg * 64;
    const int t = threadIdx.x;
    {
        const int cl = t >> 4, s4 = t & 15;
        #pragma unroll
        for (int j = 0; j < 4; ++j) {
            const int c = cl + 16 * j;
            const float4 u = *reinterpret_cast<const float4*>(
                z + (size_t)b * B_STRIDE + (size_t)(c0 + c) * S_STRIDE + s0 + s4 * 4);
            ushort4 v; v.x = f2bf(u.x); v.y = f2bf(u.y); v.z = f2bf(u.z); v.w = f2bf(u.w);
            *reinterpret_cast<ushort4*>(&lt[c][s4 * 4]) = v;
        }
    }
    __syncthreads();
    {
        const int sl = t >> 4, c4 = t & 15;
        #pragma unroll
        for (int j = 0; j < 4; ++j) {
            const int s = sl + 16 * j;
            ushort4 v;
            v.x = lt[c4 * 4 + 0][s]; v.y = lt[c4 * 4 + 1][s];
            v.z = lt[c4 * 4 + 2][s]; v.w = lt[c4 * 4 + 3][s];
            *reinterpret_cast<ushort4*>(zt + (size_t)(b * 4096 + s0 + s) * DIM + c0 + c4 * 4) = v;
        }
    }
}

// m97-style screen GEMM: BM=128 pts, BN=256 codes, BK=64, single 48 KB buffer,
// 2-barrier K-loop, global_load_lds staging with XOR chunk swizzle, 8x4 wave tile.
// Emits per-(point, 16-code-group) min of s~ = e2[k] - 2*dot_bf16 -> tmin[n][128].
__global__ __launch_bounds__(256, 2) void screen_kernel(
    const ushort_t* __restrict__ zt, const ushort_t* __restrict__ eb,
    const float* __restrict__ e2, float* __restrict__ tmin)
{
    __shared__ char lds[49152];          // A: [0,16K) = 128 rows x 8 chunks; B: [16K,48K) = 256 x 8
    __shared__ float e2s[256];
    const int tid = threadIdx.x;
    const int bm = blockIdx.x & 255, bn = blockIdx.x >> 8;   // bm fast -> eb tile L2-hot
    const int n0 = bm * 128, k0 = bn * 256;
    e2s[tid] = e2[k0 + tid];
    const int wv = tid >> 6, lane = tid & 63;
    const int col = lane & 15, quad = lane >> 4;
    const int cswz = col & 7;

    f32x4 acc[8][4];
    #pragma unroll
    for (int i = 0; i < 8; ++i)
        #pragma unroll
        for (int j = 0; j < 4; ++j) acc[i][j] = (f32x4){0.f, 0.f, 0.f, 0.f};

    for (int kc = 0; kc < 4; ++kc) {
        __syncthreads();                 // prior-iter LDS reads done before overwrite
        #pragma unroll
        for (int it = 0; it < 12; ++it) {    // 3072 x 16B chunks: A 1024, B 2048
            const int L = tid + it * 256;
            if (L < 1024) {
                const int row = L >> 3, pc = L & 7, c = pc ^ (row & 7);
                async_copy16(lds + L * 16,
                             zt + ((size_t)(n0 + row) * DIM + kc * 64 + c * 8));
            } else {
                const int L2 = L - 1024;
                const int row = L2 >> 3, pc = L2 & 7, c = pc ^ (row & 7);
                async_copy16(lds + 16384 + L2 * 16,
                             eb + ((size_t)(k0 + row) * DIM + kc * 64 + c * 8));
            }
        }
        __syncthreads();                 // drains vmcnt: staged data visible
        #pragma unroll
        for (int s = 0; s < 2; ++s) {
            const int pc = (s * 4 + quad) ^ cswz;
            bf16x8 bq[4];
            #pragma unroll
            for (int j = 0; j < 4; ++j) {
                const int brow = wv * 64 + j * 16 + col;
                bq[j] = *reinterpret_cast<const bf16x8*>(lds + 16384 + (brow * 8 + pc) * 16);
            }
            #pragma unroll
            for (int i = 0; i < 8; ++i) {
                const int arow = i * 16 + col;
                const bf16x8 af = *reinterpret_cast<const bf16x8*>(lds + (arow * 8 + pc) * 16);
                #pragma unroll
                for (int j = 0; j < 4; ++j)
                    acc[i][j] = __builtin_amdgcn_mfma_f32_16x16x32_bf16(af, bq[j], acc[i][j], 0, 0, 0);
            }
        }
    }
    // epilogue: per-16-code-group minima (reduce across the 16 col lanes)
    #pragma unroll
    for (int i = 0; i < 8; ++i) {
        #pragma unroll
        for (int j = 0; j < 4; ++j) {
            const float e2v = e2s[wv * 64 + j * 16 + col];
            float tm[4];
            #pragma unroll
            for (int r = 0; r < 4; ++r) tm[r] = fmaf(-2.f, acc[i][j][r], e2v);
            #pragma unroll
            for (int off = 1; off < 16; off <<= 1)
                #pragma unroll
                for (int r = 0; r < 4; ++r) tm[r] = fminf(tm[r], __shfl_xor(tm[r], off));
            if (col == 0) {
                const int g = bn * 16 + wv * 4 + j;     // 16-code group index, 128 total
                const int nb = n0 + i * 16 + quad * 4;  // C/D row = quad*4+r
                #pragma unroll
                for (int r = 0; r < 4; ++r) tmin[(size_t)(nb + r) * 128 + g] = tm[r];
            }
        }
    }
}

// Fused exact re-resolve + z2 + gather + loss.  Block: 64 points, coalesced z tile;
// each wave handles 16 sequential points, 4 candidate 16-code groups at a time.
__global__ __launch_bounds__(256, 2) void exact_kernel(
    const float* __restrict__ z, const float* __restrict__ emb,
    const float* __restrict__ e2, const float* __restrict__ tmin,
    float* __restrict__ outf, float* __restrict__ out_idx, float* __restrict__ partial)
{
    __shared__ float zs[64 * 260];       // [p][c] pitch 260 (65 KB): b128 row reads aligned
    const int tid = threadIdx.x;
    const int n0 = blockIdx.x * 64;
    const int b = n0 >> 12, s0 = n0 & 4095;
    {   // coalesced stage: float4 along s, all 256 channels
        const int tq = tid & 15, cg = tid >> 4;
        for (int c = cg; c < DIM; c += 16) {
            const float4 u = *reinterpret_cast<const float4*>(
                z + (size_t)b * B_STRIDE + (size_t)c * S_STRIDE + s0 + tq * 4);
            zs[(tq * 4 + 0) * 260 + c] = u.x;
            zs[(tq * 4 + 1) * 260 + c] = u.y;
            zs[(tq * 4 + 2) * 260 + c] = u.z;
            zs[(tq * 4 + 3) * 260 + c] = u.w;
        }
    }
    __syncthreads();
    const int wv = tid >> 6, lane = tid & 63;
    float lossacc = 0.f;
    for (int p = wv * 16; p < wv * 16 + 16; ++p) {
        const int n = n0 + p;
        const float* zr = &zs[p * 260];
        // np-exact z2: 16 lanes run the 8-accumulator chains, xor-tree combine in np order
        float r = 0.f;
        if (lane < 16) {
            const int h = lane >> 3, j = lane & 7;
            float v = zr[h * 128 + j];
            r = __fmul_rn(v, v);
            #pragma unroll
            for (int t = 1; t < 16; ++t) {
                v = zr[h * 128 + j + 8 * t];
                r = __fadd_rn(r, __fmul_rn(v, v));
            }
        }
        { float v = __shfl_xor(r, 1); r = __fadd_rn(r, v); }
        { float v = __shfl_xor(r, 2); r = __fadd_rn(r, v); }
        { float v = __shfl_xor(r, 4); r = __fadd_rn(r, v); }
        const float z2n = __fadd_rn(__shfl(r, 0), __shfl(r, 8));
        // threshold over 128 group minima
        const float a0 = tmin[(size_t)n * 128 + lane];
        const float a1 = tmin[(size_t)n * 128 + 64 + lane];
        float mn = fminf(a0, a1);
        #pragma unroll
        for (int off = 1; off < 64; off <<= 1) mn = fminf(mn, __shfl_xor(mn, off));
        const float thr = mn + MARGIN;
        unsigned long long M0 = __ballot(a0 <= thr);
        unsigned long long M1 = __ballot(a1 <= thr);
        float bs = FLT_MAX; int bk = 0x7FFFFFFF;
        while (M0 | M1) {
            int sel[4];
            #pragma unroll
            for (int sl = 0; sl < 4; ++sl) {          // wave-uniform extraction of <=4 groups
                int v = -1;
                if (M0) { v = __ffsll(M0) - 1; M0 &= M0 - 1; }
                else if (M1) { v = 64 + __ffsll(M1) - 1; M1 &= M1 - 1; }
                sel[sl] = v;
            }
            const int myt = sel[lane >> 4];
            if (myt >= 0) {
                const int kg = myt * 16 + (lane & 15);
                const float* er = emb + (size_t)kg * DIM;
                float dot = 0.f;                       // np-exact ascending-c fmaf chain
                #pragma unroll 8
                for (int c4 = 0; c4 < 64; ++c4) {
                    const float4 ev = reinterpret_cast<const float4*>(er)[c4];
                    const float4 zv = *reinterpret_cast<const float4*>(zr + c4 * 4);  // broadcast
                    dot = fmaf(zv.x, ev.x, dot);
                    dot = fmaf(zv.y, ev.y, dot);
                    dot = fmaf(zv.z, ev.z, dot);
                    dot = fmaf(zv.w, ev.w, dot);
                }
                const float A = __fadd_rn(z2n, e2[kg]);
                const float s = __fsub_rn(A, __fmul_rn(2.f, dot));
                if (s < bs || (s == bs && kg < bk)) { bs = s; bk = kg; }
            }
        }
        #pragma unroll
        for (int off = 1; off < 64; off <<= 1) {   // lex-min (s,k) = np.argmin
            const float os = __shfl_xor(bs, off);
            const int ok = __shfl_xor(bk, off);
            if (os < bs || (os == bs && ok < bk)) { bs = os; bk = ok; }
        }
        // gather z_q row (out[n][c] = emb[idx[n]][c]) + loss, stride-64 scalar (coalesced)
        const float* eq = emb + (size_t)bk * DIM;
        float* op = outf + (size_t)n * DIM;
        #pragma unroll
        for (int j = 0; j < 4; ++j) {
            const int c = lane + 64 * j;
            const float q = eq[c];
            op[c] = q;
            const float d = q - zr[c];
            lossacc = fmaf(d, d, lossacc);
        }
        if (lane == 0) out_idx[n] = (float)bk;
    }
    #pragma unroll
    for (int off = 1; off < 64; off <<= 1) lossacc += __shfl_xor(lossacc, off);
    if (lane == 0) atomicAdd(&partial[blockIdx.x & 63], lossacc);
}

__global__ void finalize_kernel(const float* __restrict__ partial, float* __restrict__ out_loss) {
    float v = partial[threadIdx.x];          // 64 threads
    #pragma unroll
    for (int off = 1; off < 64; off <<= 1) v += __shfl_xor(v, off);
    if (threadIdx.x == 0)
        *out_loss = v * 1.25f / (float)N_ELEM;   // (1+BETA)*mean
}

extern "C" void kernel_launch(void* const* d_in, const int* in_sizes, int n_in,
                              void* d_out, int out_size, void* d_ws, size_t ws_size,
                              hipStream_t stream) {
    const float* z = (const float*)d_in[0];
    const float* emb = (const float*)d_in[1];
    char* ws = (char*)d_ws;
    float* partial = (float*)(ws + WS_PARTIAL);
    float* e2 = (float*)(ws + WS_E2);
    ushort_t* eb = (ushort_t*)(ws + WS_EB);
    ushort_t* zt = (ushort_t*)(ws + WS_ZT);
    float* tmin = (float*)(ws + WS_TMIN);
    float* outf = (float*)d_out;
    float* out_loss = outf + N_ELEM;
    float* out_idx = outf + N_ELEM + 1;

    conv_emb_kernel<<<512, 256, 0, stream>>>(emb, eb);
    e2p_kernel<<<N_CODES / 256, 256, 0, stream>>>(emb, e2, partial);
    transpose_kernel<<<2048, 256, 0, stream>>>(z, zt);
    screen_kernel<<<2048, 256, 0, stream>>>(zt, eb, e2, tmin);
    exact_kernel<<<N_PTS / 64, 256, 0, stream>>>(z, emb, e2, tmin, outf, out_idx, partial);
    finalize_kernel<<<1, 64, 0, stream>>>(partial, out_loss);
}